// Round 15
// baseline (132.957 us; speedup 1.0000x reference)
//
#include <hip/hip_runtime.h>
#include <hip/hip_bf16.h>
#include <stdint.h>

typedef __attribute__((ext_vector_type(8))) short bf16x8;
typedef __attribute__((ext_vector_type(4))) float f32x4;
typedef __attribute__((ext_vector_type(8))) unsigned short ushort8;

__device__ __forceinline__ unsigned short cvt1(float f) {
  union { __hip_bfloat16 b; unsigned short u; } v;
  v.b = __float2bfloat16(f);
  return v.u;
}

__device__ __forceinline__ void gld_lds16(const void* g, void* l) {
  __builtin_amdgcn_global_load_lds(
      (const __attribute__((address_space(1))) unsigned int*)g,
      (__attribute__((address_space(3))) unsigned int*)l,
      16, 0, 0);
}

#define SM_OFS 12.0f  // fixed softmax offset: |q| <= sqrt(127)*|qs| ~= 11.3

// ---------------- cast + transpose W: wt[n][k] = bf16(W[k][n]) ----------------
__global__ void cast_wt_kernel(const float* __restrict__ W,
                               unsigned short* __restrict__ wt) {
  int t = blockIdx.x * blockDim.x + threadIdx.x;  // 512*512 threads
  int n = t >> 9;
  int k = t & 511;
  wt[t] = cvt1(W[k * 512 + n]);
}

// ---------------- fully fused GEMM + bias + relu + LN + softmax-partials ----------------
// Round-15: consolidate ntile-peers. Tile 128x256 (TWO LN heads per block),
// BK=32, 16 steps, 512 threads = 8 waves (2x4), wave-tile 64x64, acc[4][4].
// Per-wave regs identical to r14 (64 VGPR + 64 AGPR = 128 budget at (512,2),
// 16 waves/CU — proven fit). Blocks halve -> block-steps/CU halve (98 vs 195)
// while per-step staging grows only 24->32KB (A shared by 2x output cols).
// A: x fp32 via gld_lds (16KB), 128B rows, slot = k4 ^ (row&7)      [r14-exact]
// B: wt bf16 via gld_lds (16KB), 64B rows, slot = k8 ^ ((row>>1)&3) [r14-exact]
// Epilogue: per-head LN stats (head = wc>>1, two wc-halves each), e=exp(q-12),
// segmented per-graph atomicAdd into NU/SA[B][512].
__global__ __launch_bounds__(512, 2) void gemm_fused_kernel(
    const float* __restrict__ x,             // [N][512] fp32
    const unsigned short* __restrict__ wt,   // [512][512] bf16 (W^T)
    const float* __restrict__ bias,          // [512]
    const float* __restrict__ qs,            // [512]
    const int* __restrict__ gidx,            // [N], sorted
    float* __restrict__ NU,                  // [B][512] numerator accum
    float* __restrict__ SA,                  // [B][512] denominator accum
    int N, int mtiles) {
  __shared__ __align__(16) char smem[16384 + 16384];
  char* AsB = smem;            // fp32 A tile [128 rows][32 k], 16KB
  char* BsB = smem + 16384;    // bf16 B tile [256 rows][32 k], 16KB

  // ---- XCD-grouped bid remap: 2 ntile-peers of an mtile share bid%8 ----
  const int nfull = (mtiles >> 3) << 3;
  const int full_bids = nfull * 2;
  int mtile, ntile;
  {
    const int bid = blockIdx.x;
    if (bid < full_bids) {
      const int chunk = bid >> 4, j = bid & 15;
      mtile = (chunk << 3) + (j & 7);
      ntile = j >> 3;
    } else {
      const int j = bid - full_bids;
      const int rem = mtiles - nfull;
      mtile = nfull + j % rem;
      ntile = j / rem;
    }
  }
  const int m0 = mtile << 7;   // 128 rows
  const int n0 = ntile << 8;   // 256 cols = heads 2*ntile, 2*ntile+1

  const int tid = threadIdx.x;
  const int lane = tid & 63;
  const int wid = tid >> 6;    // 8 waves
  const int wr = wid >> 2;     // 0..1
  const int wc = wid & 3;      // 0..3

  f32x4 acc[4][4];
#pragma unroll
  for (int m = 0; m < 4; m++)
#pragma unroll
    for (int n = 0; n < 4; n++) acc[m][n] = (f32x4){0.f, 0.f, 0.f, 0.f};

  // ---- A staging: 2 x 8KB issues (512 thr x 16B), pre-swizzled source ----
  const float* aP[2];
  int aLds[2];
#pragma unroll
  for (int L = 0; L < 2; L++) {
    const int p = (L << 13) + tid * 16;
    const int row = p >> 7;              // 128B rows, [0,128)
    const int slot = (p >> 4) & 7;
    const int k4 = slot ^ (row & 7);
    aP[L] = x + (long)min(m0 + row, N - 1) * 512 + k4 * 4;
    aLds[L] = (L << 13) + (wid << 10);   // wave-uniform chunk base
  }

  // ---- B staging: 2 x 8KB issues, pre-swizzled source ----
  const unsigned short* bP[2];
  int bLds[2];
#pragma unroll
  for (int L = 0; L < 2; L++) {
    const int p = (L << 13) + tid * 16;
    const int row = p >> 6;              // 64B rows, [0,256)
    const int slot = (p >> 4) & 3;
    const int k8 = slot ^ ((row >> 1) & 3);
    bP[L] = wt + (long)(n0 + row) * 512 + k8 * 8;
    bLds[L] = (L << 13) + (wid << 10);
  }

  // ---- fragment read offsets (swizzled) ----
  const int rsel = lane & 15;
  const int k8l = lane >> 4;
  int offA[4], offB[4];
#pragma unroll
  for (int m = 0; m < 4; m++) {
    const int ra = wr * 64 + m * 16 + rsel;
    offA[m] = ra * 128 + (((k8l << 1) ^ (ra & 7)) << 4);  // pair at ^16
    const int rb = wc * 64 + m * 16 + rsel;
    offB[m] = rb * 64 + ((k8l ^ ((rb >> 1) & 3)) << 4);
  }

  // ---- K-loop: 16 steps, 2 barriers each, compiler-managed waits ----
#pragma unroll
  for (int t = 0; t < 16; t++) {
#pragma unroll
    for (int L = 0; L < 2; L++) gld_lds16(aP[L] + (t << 5), AsB + aLds[L]);
#pragma unroll
    for (int L = 0; L < 2; L++) gld_lds16(bP[L] + (t << 5), BsB + bLds[L]);
    __syncthreads();

    bf16x8 af[4], bq[4];
#pragma unroll
    for (int m = 0; m < 4; m++) {
      const f32x4 r0 = *(const f32x4*)(AsB + offA[m]);
      const f32x4 r1 = *(const f32x4*)(AsB + (offA[m] ^ 16));
      ushort8 u;
      u[0] = cvt1(r0[0]); u[1] = cvt1(r0[1]);
      u[2] = cvt1(r0[2]); u[3] = cvt1(r0[3]);
      u[4] = cvt1(r1[0]); u[5] = cvt1(r1[1]);
      u[6] = cvt1(r1[2]); u[7] = cvt1(r1[3]);
      af[m] = (bf16x8)u;
    }
#pragma unroll
    for (int n = 0; n < 4; n++) bq[n] = *(const bf16x8*)(BsB + offB[n]);
#pragma unroll
    for (int m = 0; m < 4; m++)
#pragma unroll
      for (int n = 0; n < 4; n++)
        acc[m][n] = __builtin_amdgcn_mfma_f32_16x16x32_bf16(
            af[m], bq[n], acc[m][n], 0, 0, 0);
    __syncthreads();
  }

  // ---- epilogue (aliases the A tile; loop's trailing barrier protects) ----
  int* sgidx = (int*)smem;            // [128]
  float* sS = (float*)(smem + 512);   // [128][4]
  float* sQ = (float*)(smem + 2560);  // [128][4]

  if (tid < 128) {
    const long rg = (long)m0 + tid;
    sgidx[tid] = (rg < N) ? gidx[rg] : 0x7fffffff;
  }

  const int colb = n0 + wc * 64 + rsel;
  float bval[4], qsv[4];
#pragma unroll
  for (int n = 0; n < 4; n++) {
    bval[n] = bias[colb + n * 16];
    qsv[n] = qs[colb + n * 16];
  }

  // per-row partial LN stats over this wave's 64 cols
#pragma unroll
  for (int m = 0; m < 4; m++) {
#pragma unroll
    for (int i = 0; i < 4; i++) {
      const int row_l = wr * 64 + m * 16 + (k8l << 2) + i;
      float s = 0.f, q = 0.f;
#pragma unroll
      for (int n = 0; n < 4; n++) {
        float v = fmaxf(acc[m][n][i] + bval[n], 0.f);
        s += v;
        q += v * v;
      }
#pragma unroll
      for (int d = 1; d < 16; d <<= 1) {
        s += __shfl_xor(s, d, 64);
        q += __shfl_xor(q, d, 64);
      }
      if (rsel == 0) {
        sS[row_l * 4 + wc] = s;
        sQ[row_l * 4 + wc] = q;
      }
    }
  }
  __syncthreads();

  // segmented per-graph reduction + atomics (per-wave wr-half g-range).
  // This wave's head = wc>>1: LN stats from its two wc-halves (w0=wc&2, w0+1).
  const int w0 = wc & 2;
  const int lastv = min(127, (int)((long)N - 1 - (long)m0));
  if (wr * 64 <= lastv) {
    const int gmin = sgidx[wr * 64];
    const int gmax = sgidx[min(wr * 64 + 63, lastv)];
    for (int g = gmin; g <= gmax; ++g) {
      float num[4] = {0.f, 0.f, 0.f, 0.f};
      float den[4] = {0.f, 0.f, 0.f, 0.f};
#pragma unroll
      for (int m = 0; m < 4; m++) {
#pragma unroll
        for (int i = 0; i < 4; i++) {
          const int row_l = wr * 64 + m * 16 + (k8l << 2) + i;
          if (sgidx[row_l] == g) {
            const float s = sS[row_l * 4 + w0] + sS[row_l * 4 + w0 + 1];
            const float qq = sQ[row_l * 4 + w0] + sQ[row_l * 4 + w0 + 1];
            const float mean = s * (1.f / 128.f);
            const float var = qq * (1.f / 128.f) - mean * mean;
            const float rstd = rsqrtf(var + 1e-5f);
#pragma unroll
            for (int n = 0; n < 4; n++) {
              const float v = fmaxf(acc[m][n][i] + bval[n], 0.f);
              const float qv = (v - mean) * rstd * qsv[n];
              const float e = __expf(qv - SM_OFS);
              num[n] += e * v;
              den[n] += e;
            }
          }
        }
      }
#pragma unroll
      for (int n = 0; n < 4; n++) {
        num[n] += __shfl_xor(num[n], 16, 64);
        num[n] += __shfl_xor(num[n], 32, 64);
        den[n] += __shfl_xor(den[n], 16, 64);
        den[n] += __shfl_xor(den[n], 32, 64);
      }
      if (k8l == 0) {
#pragma unroll
        for (int n = 0; n < 4; n++) {
          atomicAdd(&NU[(long)g * 512 + colb + n * 16], num[n]);
          atomicAdd(&SA[(long)g * 512 + colb + n * 16], den[n]);
        }
      }
    }
  }
}

// ---------------- finalize: out = NU / (SA + eps) ----------------
__global__ void finalize_kernel(const float* __restrict__ NU,
                                const float* __restrict__ SA,
                                float* __restrict__ out, int total) {
  const int i = blockIdx.x * blockDim.x + threadIdx.x;
  if (i < total) out[i] = NU[i] / (SA[i] + 1e-16f);
}

extern "C" void kernel_launch(void* const* d_in, const int* in_sizes, int n_in,
                              void* d_out, int out_size, void* d_ws, size_t ws_size,
                              hipStream_t stream) {
  const float* x = (const float*)d_in[0];
  const float* W = (const float*)d_in[1];
  const float* bias = (const float*)d_in[2];
  const float* qs = (const float*)d_in[3];
  const int* gidx = (const int*)d_in[4];
  const int N = in_sizes[0] / 512;
  const int B = out_size / 512;
  float* out = (float*)d_out;

  char* ws = (char*)d_ws;
  size_t off = 0;
  auto alloc = [&](size_t bytes) {
    char* p = ws + off;
    off += (bytes + 255) & ~(size_t)255;
    return p;
  };
  unsigned short* wt = (unsigned short*)alloc((size_t)512 * 512 * 2);
  float* accbuf = (float*)alloc((size_t)B * 512 * 2 * sizeof(float));
  float* NU = accbuf;
  float* SA = accbuf + (size_t)B * 512;
  (void)ws_size;  // need ~2.6 MB

  hipMemsetAsync(accbuf, 0, (size_t)B * 512 * 2 * sizeof(float), stream);
  cast_wt_kernel<<<(512 * 512) / 256, 256, 0, stream>>>(W, wt);
  const int mtiles = (N + 127) / 128;
  gemm_fused_kernel<<<mtiles * 2, 512, 0, stream>>>(x, wt, bias, qs, gidx, NU,
                                                    SA, N, mtiles);
  const int total = B * 512;
  finalize_kernel<<<(total + 255) / 256, 256, 0, stream>>>(NU, SA, out, total);
}

// Round 16
// 132.801 us; speedup vs baseline: 1.0012x; 1.0012x over previous
//
#include <hip/hip_runtime.h>
#include <hip/hip_bf16.h>
#include <stdint.h>

typedef __attribute__((ext_vector_type(8))) short bf16x8;
typedef __attribute__((ext_vector_type(4))) float f32x4;
typedef __attribute__((ext_vector_type(8))) unsigned short ushort8;

__device__ __forceinline__ unsigned short cvt1(float f) {
  union { __hip_bfloat16 b; unsigned short u; } v;
  v.b = __float2bfloat16(f);
  return v.u;
}

__device__ __forceinline__ void gld_lds16(const void* g, void* l) {
  __builtin_amdgcn_global_load_lds(
      (const __attribute__((address_space(1))) unsigned int*)g,
      (__attribute__((address_space(3))) unsigned int*)l,
      16, 0, 0);
}

#define SM_OFS 12.0f  // fixed softmax offset: |q| <= sqrt(127)*|qs| ~= 11.3

// ---------------- cast + transpose W: wt[n][k] = bf16(W[k][n]) ----------------
__global__ void cast_wt_kernel(const float* __restrict__ W,
                               unsigned short* __restrict__ wt) {
  int t = blockIdx.x * blockDim.x + threadIdx.x;  // 512*512 threads
  int n = t >> 9;
  int k = t & 511;
  wt[t] = cvt1(W[k * 512 + n]);
}

// ---------------- fully fused GEMM + bias + relu + LN + softmax-partials ----------------
// Round-15: consolidate ntile-peers. Tile 128x256 (TWO LN heads per block),
// BK=32, 16 steps, 512 threads = 8 waves (2x4), wave-tile 64x64, acc[4][4].
// Per-wave regs identical to r14 (64 VGPR + 64 AGPR = 128 budget at (512,2),
// 16 waves/CU — proven fit). Blocks halve -> block-steps/CU halve (98 vs 195)
// while per-step staging grows only 24->32KB (A shared by 2x output cols).
// A: x fp32 via gld_lds (16KB), 128B rows, slot = k4 ^ (row&7)      [r14-exact]
// B: wt bf16 via gld_lds (16KB), 64B rows, slot = k8 ^ ((row>>1)&3) [r14-exact]
// Epilogue: per-head LN stats (head = wc>>1, two wc-halves each), e=exp(q-12),
// segmented per-graph atomicAdd into NU/SA[B][512].
__global__ __launch_bounds__(512, 2) void gemm_fused_kernel(
    const float* __restrict__ x,             // [N][512] fp32
    const unsigned short* __restrict__ wt,   // [512][512] bf16 (W^T)
    const float* __restrict__ bias,          // [512]
    const float* __restrict__ qs,            // [512]
    const int* __restrict__ gidx,            // [N], sorted
    float* __restrict__ NU,                  // [B][512] numerator accum
    float* __restrict__ SA,                  // [B][512] denominator accum
    int N, int mtiles) {
  __shared__ __align__(16) char smem[16384 + 16384];
  char* AsB = smem;            // fp32 A tile [128 rows][32 k], 16KB
  char* BsB = smem + 16384;    // bf16 B tile [256 rows][32 k], 16KB

  // ---- XCD-grouped bid remap: 2 ntile-peers of an mtile share bid%8 ----
  const int nfull = (mtiles >> 3) << 3;
  const int full_bids = nfull * 2;
  int mtile, ntile;
  {
    const int bid = blockIdx.x;
    if (bid < full_bids) {
      const int chunk = bid >> 4, j = bid & 15;
      mtile = (chunk << 3) + (j & 7);
      ntile = j >> 3;
    } else {
      const int j = bid - full_bids;
      const int rem = mtiles - nfull;
      mtile = nfull + j % rem;
      ntile = j / rem;
    }
  }
  const int m0 = mtile << 7;   // 128 rows
  const int n0 = ntile << 8;   // 256 cols = heads 2*ntile, 2*ntile+1

  const int tid = threadIdx.x;
  const int lane = tid & 63;
  const int wid = tid >> 6;    // 8 waves
  const int wr = wid >> 2;     // 0..1
  const int wc = wid & 3;      // 0..3

  f32x4 acc[4][4];
#pragma unroll
  for (int m = 0; m < 4; m++)
#pragma unroll
    for (int n = 0; n < 4; n++) acc[m][n] = (f32x4){0.f, 0.f, 0.f, 0.f};

  // ---- A staging: 2 x 8KB issues (512 thr x 16B), pre-swizzled source ----
  const float* aP[2];
  int aLds[2];
#pragma unroll
  for (int L = 0; L < 2; L++) {
    const int p = (L << 13) + tid * 16;
    const int row = p >> 7;              // 128B rows, [0,128)
    const int slot = (p >> 4) & 7;
    const int k4 = slot ^ (row & 7);
    aP[L] = x + (long)min(m0 + row, N - 1) * 512 + k4 * 4;
    aLds[L] = (L << 13) + (wid << 10);   // wave-uniform chunk base
  }

  // ---- B staging: 2 x 8KB issues, pre-swizzled source ----
  const unsigned short* bP[2];
  int bLds[2];
#pragma unroll
  for (int L = 0; L < 2; L++) {
    const int p = (L << 13) + tid * 16;
    const int row = p >> 6;              // 64B rows, [0,256)
    const int slot = (p >> 4) & 3;
    const int k8 = slot ^ ((row >> 1) & 3);
    bP[L] = wt + (long)(n0 + row) * 512 + k8 * 8;
    bLds[L] = (L << 13) + (wid << 10);
  }

  // ---- fragment read offsets (swizzled) ----
  const int rsel = lane & 15;
  const int k8l = lane >> 4;
  int offA[4], offB[4];
#pragma unroll
  for (int m = 0; m < 4; m++) {
    const int ra = wr * 64 + m * 16 + rsel;
    offA[m] = ra * 128 + (((k8l << 1) ^ (ra & 7)) << 4);  // pair at ^16
    const int rb = wc * 64 + m * 16 + rsel;
    offB[m] = rb * 64 + ((k8l ^ ((rb >> 1) & 3)) << 4);
  }

  // ---- K-loop: 16 steps, 2 barriers each, compiler-managed waits ----
#pragma unroll
  for (int t = 0; t < 16; t++) {
#pragma unroll
    for (int L = 0; L < 2; L++) gld_lds16(aP[L] + (t << 5), AsB + aLds[L]);
#pragma unroll
    for (int L = 0; L < 2; L++) gld_lds16(bP[L] + (t << 5), BsB + bLds[L]);
    __syncthreads();

    bf16x8 af[4], bq[4];
#pragma unroll
    for (int m = 0; m < 4; m++) {
      const f32x4 r0 = *(const f32x4*)(AsB + offA[m]);
      const f32x4 r1 = *(const f32x4*)(AsB + (offA[m] ^ 16));
      ushort8 u;
      u[0] = cvt1(r0[0]); u[1] = cvt1(r0[1]);
      u[2] = cvt1(r0[2]); u[3] = cvt1(r0[3]);
      u[4] = cvt1(r1[0]); u[5] = cvt1(r1[1]);
      u[6] = cvt1(r1[2]); u[7] = cvt1(r1[3]);
      af[m] = (bf16x8)u;
    }
#pragma unroll
    for (int n = 0; n < 4; n++) bq[n] = *(const bf16x8*)(BsB + offB[n]);
#pragma unroll
    for (int m = 0; m < 4; m++)
#pragma unroll
      for (int n = 0; n < 4; n++)
        acc[m][n] = __builtin_amdgcn_mfma_f32_16x16x32_bf16(
            af[m], bq[n], acc[m][n], 0, 0, 0);
    __syncthreads();
  }

  // ---- epilogue (aliases the A tile; loop's trailing barrier protects) ----
  int* sgidx = (int*)smem;            // [128]
  float* sS = (float*)(smem + 512);   // [128][4]
  float* sQ = (float*)(smem + 2560);  // [128][4]

  if (tid < 128) {
    const long rg = (long)m0 + tid;
    sgidx[tid] = (rg < N) ? gidx[rg] : 0x7fffffff;
  }

  const int colb = n0 + wc * 64 + rsel;
  float bval[4], qsv[4];
#pragma unroll
  for (int n = 0; n < 4; n++) {
    bval[n] = bias[colb + n * 16];
    qsv[n] = qs[colb + n * 16];
  }

  // per-row partial LN stats over this wave's 64 cols
#pragma unroll
  for (int m = 0; m < 4; m++) {
#pragma unroll
    for (int i = 0; i < 4; i++) {
      const int row_l = wr * 64 + m * 16 + (k8l << 2) + i;
      float s = 0.f, q = 0.f;
#pragma unroll
      for (int n = 0; n < 4; n++) {
        float v = fmaxf(acc[m][n][i] + bval[n], 0.f);
        s += v;
        q += v * v;
      }
#pragma unroll
      for (int d = 1; d < 16; d <<= 1) {
        s += __shfl_xor(s, d, 64);
        q += __shfl_xor(q, d, 64);
      }
      if (rsel == 0) {
        sS[row_l * 4 + wc] = s;
        sQ[row_l * 4 + wc] = q;
      }
    }
  }
  __syncthreads();

  // segmented per-graph reduction + atomics (per-wave wr-half g-range).
  // This wave's head = wc>>1: LN stats from its two wc-halves (w0=wc&2, w0+1).
  const int w0 = wc & 2;
  const int lastv = min(127, (int)((long)N - 1 - (long)m0));
  if (wr * 64 <= lastv) {
    const int gmin = sgidx[wr * 64];
    const int gmax = sgidx[min(wr * 64 + 63, lastv)];
    for (int g = gmin; g <= gmax; ++g) {
      float num[4] = {0.f, 0.f, 0.f, 0.f};
      float den[4] = {0.f, 0.f, 0.f, 0.f};
#pragma unroll
      for (int m = 0; m < 4; m++) {
#pragma unroll
        for (int i = 0; i < 4; i++) {
          const int row_l = wr * 64 + m * 16 + (k8l << 2) + i;
          if (sgidx[row_l] == g) {
            const float s = sS[row_l * 4 + w0] + sS[row_l * 4 + w0 + 1];
            const float qq = sQ[row_l * 4 + w0] + sQ[row_l * 4 + w0 + 1];
            const float mean = s * (1.f / 128.f);
            const float var = qq * (1.f / 128.f) - mean * mean;
            const float rstd = rsqrtf(var + 1e-5f);
#pragma unroll
            for (int n = 0; n < 4; n++) {
              const float v = fmaxf(acc[m][n][i] + bval[n], 0.f);
              const float qv = (v - mean) * rstd * qsv[n];
              const float e = __expf(qv - SM_OFS);
              num[n] += e * v;
              den[n] += e;
            }
          }
        }
      }
#pragma unroll
      for (int n = 0; n < 4; n++) {
        num[n] += __shfl_xor(num[n], 16, 64);
        num[n] += __shfl_xor(num[n], 32, 64);
        den[n] += __shfl_xor(den[n], 16, 64);
        den[n] += __shfl_xor(den[n], 32, 64);
      }
      if (k8l == 0) {
#pragma unroll
        for (int n = 0; n < 4; n++) {
          atomicAdd(&NU[(long)g * 512 + colb + n * 16], num[n]);
          atomicAdd(&SA[(long)g * 512 + colb + n * 16], den[n]);
        }
      }
    }
  }
}

// ---------------- finalize: out = NU / (SA + eps) ----------------
__global__ void finalize_kernel(const float* __restrict__ NU,
                                const float* __restrict__ SA,
                                float* __restrict__ out, int total) {
  const int i = blockIdx.x * blockDim.x + threadIdx.x;
  if (i < total) out[i] = NU[i] / (SA[i] + 1e-16f);
}

extern "C" void kernel_launch(void* const* d_in, const int* in_sizes, int n_in,
                              void* d_out, int out_size, void* d_ws, size_t ws_size,
                              hipStream_t stream) {
  const float* x = (const float*)d_in[0];
  const float* W = (const float*)d_in[1];
  const float* bias = (const float*)d_in[2];
  const float* qs = (const float*)d_in[3];
  const int* gidx = (const int*)d_in[4];
  const int N = in_sizes[0] / 512;
  const int B = out_size / 512;
  float* out = (float*)d_out;

  char* ws = (char*)d_ws;
  size_t off = 0;
  auto alloc = [&](size_t bytes) {
    char* p = ws + off;
    off += (bytes + 255) & ~(size_t)255;
    return p;
  };
  unsigned short* wt = (unsigned short*)alloc((size_t)512 * 512 * 2);
  float* accbuf = (float*)alloc((size_t)B * 512 * 2 * sizeof(float));
  float* NU = accbuf;
  float* SA = accbuf + (size_t)B * 512;
  (void)ws_size;  // need ~2.6 MB

  hipMemsetAsync(accbuf, 0, (size_t)B * 512 * 2 * sizeof(float), stream);
  cast_wt_kernel<<<(512 * 512) / 256, 256, 0, stream>>>(W, wt);
  const int mtiles = (N + 127) / 128;
  gemm_fused_kernel<<<mtiles * 2, 512, 0, stream>>>(x, wt, bias, qs, gidx, NU,
                                                    SA, N, mtiles);
  const int total = B * 512;
  finalize_kernel<<<(total + 255) / 256, 256, 0, stream>>>(NU, SA, out, total);
}

// Round 17
// 127.123 us; speedup vs baseline: 1.0459x; 1.0447x over previous
//
#include <hip/hip_runtime.h>
#include <hip/hip_bf16.h>
#include <stdint.h>

typedef __attribute__((ext_vector_type(8))) short bf16x8;
typedef __attribute__((ext_vector_type(4))) float f32x4;
typedef __attribute__((ext_vector_type(8))) unsigned short ushort8;

__device__ __forceinline__ unsigned short cvt1(float f) {
  union { __hip_bfloat16 b; unsigned short u; } v;
  v.b = __float2bfloat16(f);
  return v.u;
}

__device__ __forceinline__ void gld_lds16(const void* g, void* l) {
  __builtin_amdgcn_global_load_lds(
      (const __attribute__((address_space(1))) unsigned int*)g,
      (__attribute__((address_space(3))) unsigned int*)l,
      16, 0, 0);
}

#define SM_OFS 12.0f  // fixed softmax offset: |q| <= sqrt(127)*|qs| ~= 11.3

// ---------------- cast + transpose W: wt[n][k] = bf16(W[k][n]) ----------------
__global__ void cast_wt_kernel(const float* __restrict__ W,
                               unsigned short* __restrict__ wt) {
  int t = blockIdx.x * blockDim.x + threadIdx.x;  // 512*512 threads
  int n = t >> 9;
  int k = t & 511;
  wt[t] = cvt1(W[k * 512 + n]);
}

// ---------------- fully fused GEMM + bias + relu + LN + softmax-partials ----------------
// r14 geometry + catalog T3 "minimum 2-phase": double-buffered LDS, per tile
//   STAGE(buf^1, t+1)  ->  compute(buf)  ->  vmcnt(0) + ONE s_barrier.
// Stage(t+1) now has a full compute phase (~500-700cyc) of latency cover,
// vs r14's zero (stage and consume in the same step). 48KB LDS keeps
// 3 blocks/CU of TLP (the thing r4/r10 prefetch attempts gave up).
// Tile 128x128 (BN=128 == one LN head), BK=32, 16 steps, 4 waves (2x2),
// wave-tile 64x64, acc[4][4] (64 AGPR; VGPR ~64 at (256,3) budget ~170).
// A: x fp32 via gld_lds, 128B rows, slot = k4 ^ (row&7)      [r14-exact]
// B: wt bf16 via gld_lds, 64B rows, slot = k8 ^ ((row>>1)&3) [r14-exact]
// Epilogue (validated r7/r9/r14): LN stats, e=exp(q-12), segmented atomicAdd.
__global__ __launch_bounds__(256, 3) void gemm_fused_kernel(
    const float* __restrict__ x,             // [N][512] fp32
    const unsigned short* __restrict__ wt,   // [512][512] bf16 (W^T)
    const float* __restrict__ bias,          // [512]
    const float* __restrict__ qs,            // [512]
    const int* __restrict__ gidx,            // [N], sorted
    float* __restrict__ NU,                  // [B][512] numerator accum
    float* __restrict__ SA,                  // [B][512] denominator accum
    int N, int mtiles) {
  __shared__ __align__(16) char smem[2 * 24576];  // buf: [A 16KB | B 8KB] x2

  // ---- XCD-grouped bid remap: 4 ntile-peers of an mtile share bid%8 ----
  const int nfull = (mtiles >> 3) << 3;
  const int full_bids = nfull * 4;
  int mtile, ntile;
  {
    const int bid = blockIdx.x;
    if (bid < full_bids) {
      const int chunk = bid >> 5, j = bid & 31;
      mtile = (chunk << 3) + (j & 7);
      ntile = j >> 3;
    } else {
      const int j = bid - full_bids;
      const int rem = mtiles - nfull;
      mtile = nfull + j % rem;
      ntile = j / rem;
    }
  }
  const int m0 = mtile << 7;
  const int n0 = ntile << 7;

  const int tid = threadIdx.x;
  const int lane = tid & 63;
  const int wid = tid >> 6;
  const int wr = wid >> 1;
  const int wc = wid & 1;

  f32x4 acc[4][4];
#pragma unroll
  for (int m = 0; m < 4; m++)
#pragma unroll
    for (int n = 0; n < 4; n++) acc[m][n] = (f32x4){0.f, 0.f, 0.f, 0.f};

  // ---- A staging: 4 x 4KB regions, pre-swizzled global source ----
  const float* aP[4];
  int aLds[4];
#pragma unroll
  for (int L = 0; L < 4; L++) {
    const int p = (L << 12) + tid * 16;
    const int row = p >> 7;              // 128B rows
    const int slot = (p >> 4) & 7;
    const int k4 = slot ^ (row & 7);
    aP[L] = x + (long)min(m0 + row, N - 1) * 512 + k4 * 4;
    aLds[L] = (L << 12) + (wid << 10);   // wave-uniform chunk base
  }

  // ---- B staging: 2 x 4KB regions, pre-swizzled global source ----
  const unsigned short* bP[2];
  int bLds[2];
#pragma unroll
  for (int L = 0; L < 2; L++) {
    const int p = (L << 12) + tid * 16;
    const int row = p >> 6;              // 64B rows
    const int slot = (p >> 4) & 3;
    const int k8 = slot ^ ((row >> 1) & 3);
    bP[L] = wt + (long)(n0 + row) * 512 + k8 * 8;
    bLds[L] = (L << 12) + (wid << 10);
  }

  // ---- fragment read offsets (swizzled) ----
  const int rsel = lane & 15;
  const int k8l = lane >> 4;
  int offA[4], offB[4];
#pragma unroll
  for (int m = 0; m < 4; m++) {
    const int ra = wr * 64 + m * 16 + rsel;
    offA[m] = ra * 128 + (((k8l << 1) ^ (ra & 7)) << 4);  // pair at ^16
    const int rb = wc * 64 + m * 16 + rsel;
    offB[m] = rb * 64 + ((k8l ^ ((rb >> 1) & 3)) << 4);
  }

#define STAGE(buf, tt)                                                     \
  {                                                                        \
    _Pragma("unroll") for (int L = 0; L < 4; L++)                          \
        gld_lds16(aP[L] + ((tt) << 5), smem + (buf) * 24576 + aLds[L]);    \
    _Pragma("unroll") for (int L = 0; L < 2; L++)                          \
        gld_lds16(bP[L] + ((tt) << 5),                                     \
                  smem + (buf) * 24576 + 16384 + bLds[L]);                 \
  }

  // ---- prologue: stage tile 0, drain, barrier ----
  STAGE(0, 0);
  asm volatile("s_waitcnt vmcnt(0)" ::: "memory");
  __builtin_amdgcn_sched_barrier(0);
  __builtin_amdgcn_s_barrier();

  // ---- K-loop: 16 steps; per step: STAGE(next) -> compute(cur) -> vmcnt(0)
  //      -> ONE barrier.  Stage has a full compute phase of latency cover. ----
#pragma unroll
  for (int t = 0; t < 16; t++) {
    if (t < 15) STAGE((t + 1) & 1, t + 1);

    const char* AsB = smem + (t & 1) * 24576;
    const char* BsB = AsB + 16384;
    bf16x8 af[4], bq[4];
#pragma unroll
    for (int m = 0; m < 4; m++) {
      const f32x4 r0 = *(const f32x4*)(AsB + offA[m]);
      const f32x4 r1 = *(const f32x4*)(AsB + (offA[m] ^ 16));
      ushort8 u;
      u[0] = cvt1(r0[0]); u[1] = cvt1(r0[1]);
      u[2] = cvt1(r0[2]); u[3] = cvt1(r0[3]);
      u[4] = cvt1(r1[0]); u[5] = cvt1(r1[1]);
      u[6] = cvt1(r1[2]); u[7] = cvt1(r1[3]);
      af[m] = (bf16x8)u;
    }
#pragma unroll
    for (int n = 0; n < 4; n++) bq[n] = *(const bf16x8*)(BsB + offB[n]);
#pragma unroll
    for (int m = 0; m < 4; m++)
#pragma unroll
      for (int n = 0; n < 4; n++)
        acc[m][n] = __builtin_amdgcn_mfma_f32_16x16x32_bf16(
            af[m], bq[n], acc[m][n], 0, 0, 0);

    if (t < 15) {
      asm volatile("s_waitcnt vmcnt(0)" ::: "memory");  // next tile landed
      __builtin_amdgcn_sched_barrier(0);
      __builtin_amdgcn_s_barrier();
    }
  }
#undef STAGE

  // ---- epilogue (aliases buf0; sync first since loop ends barrier-less) ----
  __syncthreads();
  int* sgidx = (int*)smem;            // [128]
  float* sS = (float*)(smem + 512);   // [128][2]
  float* sQ = (float*)(smem + 1536);  // [128][2]

  if (tid < 128) {
    const long rg = (long)m0 + tid;
    sgidx[tid] = (rg < N) ? gidx[rg] : 0x7fffffff;
  }

  const int colb = n0 + wc * 64 + rsel;
  float bval[4], qsv[4];
#pragma unroll
  for (int n = 0; n < 4; n++) {
    bval[n] = bias[colb + n * 16];
    qsv[n] = qs[colb + n * 16];
  }

  // per-row partial LN stats over this wave's 64 cols
#pragma unroll
  for (int m = 0; m < 4; m++) {
#pragma unroll
    for (int i = 0; i < 4; i++) {
      const int row_l = wr * 64 + m * 16 + (k8l << 2) + i;
      float s = 0.f, q = 0.f;
#pragma unroll
      for (int n = 0; n < 4; n++) {
        float v = fmaxf(acc[m][n][i] + bval[n], 0.f);
        s += v;
        q += v * v;
      }
#pragma unroll
      for (int d = 1; d < 16; d <<= 1) {
        s += __shfl_xor(s, d, 64);
        q += __shfl_xor(q, d, 64);
      }
      if (rsel == 0) {
        sS[row_l * 2 + wc] = s;
        sQ[row_l * 2 + wc] = q;
      }
    }
  }
  __syncthreads();

  // segmented per-graph reduction + atomics (per-wave wr-half g-range)
  const int lastv = min(127, (int)((long)N - 1 - (long)m0));
  if (wr * 64 <= lastv) {
    const int gmin = sgidx[wr * 64];
    const int gmax = sgidx[min(wr * 64 + 63, lastv)];
    for (int g = gmin; g <= gmax; ++g) {
      float num[4] = {0.f, 0.f, 0.f, 0.f};
      float den[4] = {0.f, 0.f, 0.f, 0.f};
#pragma unroll
      for (int m = 0; m < 4; m++) {
#pragma unroll
        for (int i = 0; i < 4; i++) {
          const int row_l = wr * 64 + m * 16 + (k8l << 2) + i;
          if (sgidx[row_l] == g) {
            const float s = sS[row_l * 2] + sS[row_l * 2 + 1];
            const float qq = sQ[row_l * 2] + sQ[row_l * 2 + 1];
            const float mean = s * (1.f / 128.f);
            const float var = qq * (1.f / 128.f) - mean * mean;
            const float rstd = rsqrtf(var + 1e-5f);
#pragma unroll
            for (int n = 0; n < 4; n++) {
              const float v = fmaxf(acc[m][n][i] + bval[n], 0.f);
              const float qv = (v - mean) * rstd * qsv[n];
              const float e = __expf(qv - SM_OFS);
              num[n] += e * v;
              den[n] += e;
            }
          }
        }
      }
#pragma unroll
      for (int n = 0; n < 4; n++) {
        num[n] += __shfl_xor(num[n], 16, 64);
        num[n] += __shfl_xor(num[n], 32, 64);
        den[n] += __shfl_xor(den[n], 16, 64);
        den[n] += __shfl_xor(den[n], 32, 64);
      }
      if (k8l == 0) {
#pragma unroll
        for (int n = 0; n < 4; n++) {
          atomicAdd(&NU[(long)g * 512 + colb + n * 16], num[n]);
          atomicAdd(&SA[(long)g * 512 + colb + n * 16], den[n]);
        }
      }
    }
  }
}

// ---------------- finalize: out = NU / (SA + eps) ----------------
__global__ void finalize_kernel(const float* __restrict__ NU,
                                const float* __restrict__ SA,
                                float* __restrict__ out, int total) {
  const int i = blockIdx.x * blockDim.x + threadIdx.x;
  if (i < total) out[i] = NU[i] / (SA[i] + 1e-16f);
}

extern "C" void kernel_launch(void* const* d_in, const int* in_sizes, int n_in,
                              void* d_out, int out_size, void* d_ws, size_t ws_size,
                              hipStream_t stream) {
  const float* x = (const float*)d_in[0];
  const float* W = (const float*)d_in[1];
  const float* bias = (const float*)d_in[2];
  const float* qs = (const float*)d_in[3];
  const int* gidx = (const int*)d_in[4];
  const int N = in_sizes[0] / 512;
  const int B = out_size / 512;
  float* out = (float*)d_out;

  char* ws = (char*)d_ws;
  size_t off = 0;
  auto alloc = [&](size_t bytes) {
    char* p = ws + off;
    off += (bytes + 255) & ~(size_t)255;
    return p;
  };
  unsigned short* wt = (unsigned short*)alloc((size_t)512 * 512 * 2);
  float* accbuf = (float*)alloc((size_t)B * 512 * 2 * sizeof(float));
  float* NU = accbuf;
  float* SA = accbuf + (size_t)B * 512;
  (void)ws_size;  // need ~2.6 MB

  hipMemsetAsync(accbuf, 0, (size_t)B * 512 * 2 * sizeof(float), stream);
  cast_wt_kernel<<<(512 * 512) / 256, 256, 0, stream>>>(W, wt);
  const int mtiles = (N + 127) / 128;
  gemm_fused_kernel<<<mtiles * 4, 256, 0, stream>>>(x, wt, bias, qs, gidx, NU,
                                                    SA, N, mtiles);
  const int total = B * 512;
  finalize_kernel<<<(total + 255) / 256, 256, 0, stream>>>(NU, SA, out, total);
}